// Round 8
// baseline (272.536 us; speedup 1.0000x reference)
//
#include <hip/hip_runtime.h>
#include <math.h>

#define NB 128     // batch
#define NC 64      // channels
#define NT 128     // segment length
#define HIDN 128   // hidden
#define NE 64      // attn embed
#define NHD 4      // heads
#define HD 16      // head dim
#define NBLK 128   // mega-kernel grid (1 block per batch, <= 256 CUs -> all resident)

// ---------------------------------------------------------------------------
// 1. Analytic signal (unchanged from R6/R7; bit-identical math; [b][c][t]).
// ---------------------------------------------------------------------------
__global__ void analytic_kernel(const float* __restrict__ eeg,
                                float* __restrict__ re, float* __restrict__ im) {
    int row = blockIdx.x;            // b*NC + c
    int t = threadIdx.x;             // 0..127
    __shared__ float xs[NT];
    __shared__ double cotv[64];
    xs[t] = eeg[row * NT + t];
    if (t < 64) {
        double d = (double)(2 * t + 1);
        double a = 3.14159265358979323846 * d / 128.0;
        cotv[t] = cos(a) / sin(a);
    }
    __syncthreads();
    double ar = 0.0, ai = 0.0;
    #pragma unroll
    for (int m = 0; m < 64; ++m) {
        int d = 2 * m + 1;
        int s = (t - d) & 127;
        double xv = (double)xs[s];
        ar += xv;
        ai += cotv[m] * xv;
    }
    double rr = (double)xs[t] + ar * (1.0 / 64.0);
    double ii = ai * (1.0 / 64.0);
    re[row * NT + t] = (float)rr;
    im[row * NT + t] = (float)ii;
}

// ---------------------------------------------------------------------------
// Device-scope grid barrier. Safe: grid=128 blocks, 1 block/CU (LDS-bound),
// 256 CUs -> all blocks resident; single-use counter per barrier slot,
// reset by hipMemsetAsync each launch.
// ---------------------------------------------------------------------------
__device__ __forceinline__ void grid_bar(int* bar, int nblk) {
    __threadfence();                 // release this block's global stores
    __syncthreads();
    if (threadIdx.x == 0) {
        __hip_atomic_fetch_add(bar, 1, __ATOMIC_ACQ_REL, __HIP_MEMORY_SCOPE_AGENT);
        while (__hip_atomic_load(bar, __ATOMIC_ACQUIRE, __HIP_MEMORY_SCOPE_AGENT) < nblk)
            __builtin_amdgcn_s_sleep(8);
    }
    __syncthreads();
    __threadfence();                 // acquire: invalidate stale cached lines
}

// ---------------------------------------------------------------------------
// 2. MEGA kernel: pli -> gcn1 -> [grid bar] -> gcn2 -> [grid bar] -> attn.
//    One block per batch, 1024 threads, ~146 KB LDS (hand-overlaid regions).
//    All per-phase arithmetic expressions identical to R7 kernels.
// ---------------------------------------------------------------------------
__global__ __launch_bounds__(1024, 1) void mega_kernel(
        const float* __restrict__ eeg,
        const float* __restrict__ w_re, const float* __restrict__ w_im,
        const float* __restrict__ g1w, const float* __restrict__ g1b,
        const float* __restrict__ g2w, const float* __restrict__ g2b,
        const float* __restrict__ bn1g, const float* __restrict__ bn1b,
        const float* __restrict__ bn2g, const float* __restrict__ bn2b,
        const float* __restrict__ wiw, const float* __restrict__ wib,
        const float* __restrict__ wow, const float* __restrict__ wob,
        float* __restrict__ wpli, float* __restrict__ feat,
        float* __restrict__ w_x1,
        double* __restrict__ dpart1, double* __restrict__ dpart2,
        int* __restrict__ bar) {
    int b = blockIdx.x;
    int tid = threadIdx.x;           // 0..1023
    int lane = tid & 63, wv = tid >> 6;

    __shared__ __align__(16) char smem[149504];
    char* U = smem;                          // 128 KB union region
    float* arow  = (float*)(smem + 131072);  // [64][68] 17.4 KB, persistent G1+G2
    float* deg_s = (float*)(smem + 148480);  // [64]
    float* dn_s  = (float*)(smem + 148736);  // [64]
    float* stat_s= (float*)(smem + 148992);  // [64][2]

    // ===================== PHASE P: PLI (+deg) =====================
    {
        float4* re4_s = (float4*)(U);            // 32 KB
        float4* im4_s = (float4*)(U + 32768);    // 32 KB
        int*    pacc  = (int*)(U + 65536);       // [4][4][4][64] 16 KB
        const float* reb = w_re + b * 8192;
        const float* imb = w_im + b * 8192;
        for (int idx4 = tid; idx4 < 2048; idx4 += 1024) {
            int c = idx4 >> 5, t4 = idx4 & 31;
            int slot = c * 32 + (t4 ^ (c & 31));
            re4_s[slot] = ((const float4*)reb)[idx4];
            im4_s[slot] = ((const float4*)imb)[idx4];
        }
        __syncthreads();
        int q = tid >> 8, t8 = tid & 255, w = t8 >> 6, j = t8 & 63;
        for (int rnd = 0; rnd < 4; ++rnd) {
            int i0 = (rnd * 4 + q) << 2;
            int acc0 = 0, acc1 = 0, acc2 = 0, acc3 = 0;
            #pragma unroll
            for (int tt = 0; tt < 8; ++tt) {
                int t4 = w * 8 + tt;
                float4 rj = re4_s[j * 32 + (t4 ^ (j & 31))];
                float4 ij = im4_s[j * 32 + (t4 ^ (j & 31))];
                #pragma unroll
                for (int di = 0; di < 4; ++di) {
                    int i = i0 + di;
                    float4 ri = re4_s[i * 32 + (t4 ^ (i & 31))];
                    float4 ii = im4_s[i * 32 + (t4 ^ (i & 31))];
                    float c0 = ii.x * rj.x - ri.x * ij.x;
                    float c1 = ii.y * rj.y - ri.y * ij.y;
                    float c2 = ii.z * rj.z - ri.z * ij.z;
                    float c3 = ii.w * rj.w - ri.w * ij.w;
                    int d = ((c0 > 0.f) ? 1 : ((c0 < 0.f) ? -1 : 0))
                          + ((c1 > 0.f) ? 1 : ((c1 < 0.f) ? -1 : 0))
                          + ((c2 > 0.f) ? 1 : ((c2 < 0.f) ? -1 : 0))
                          + ((c3 > 0.f) ? 1 : ((c3 < 0.f) ? -1 : 0));
                    if (di == 0) acc0 += d;
                    else if (di == 1) acc1 += d;
                    else if (di == 2) acc2 += d;
                    else acc3 += d;
                }
            }
            pacc[((q * 4 + w) * 4 + 0) * 64 + j] = acc0;
            pacc[((q * 4 + w) * 4 + 1) * 64 + j] = acc1;
            pacc[((q * 4 + w) * 4 + 2) * 64 + j] = acc2;
            pacc[((q * 4 + w) * 4 + 3) * 64 + j] = acc3;
            __syncthreads();
            int a = pacc[((q * 4 + 0) * 4 + w) * 64 + j]
                  + pacc[((q * 4 + 1) * 4 + w) * 64 + j]
                  + pacc[((q * 4 + 2) * 4 + w) * 64 + j]
                  + pacc[((q * 4 + 3) * 4 + w) * 64 + j];
            float p = fabsf((float)a * (1.f / (float)NT));
            int i = i0 + w;
            if (j == i) p = 0.f;
            wpli[b * 4096 + i * 64 + j] = p;
            float s = p;
            #pragma unroll
            for (int off = 32; off > 0; off >>= 1) s += __shfl_down(s, off);
            if (j == 0) deg_s[i] = s;
            __syncthreads();
        }
    }

    // ===================== PHASE G1: GCN layer 1 =====================
    {
        float* xs  = (float*)(U);                // [64][128] 32 KB (eeg)
        float* WsT = (float*)(U + 32768);        // [128][128] 64 KB
        float* sup = (float*)(U + 98304);        // [64][128] 32 KB
        if (tid < 64)
            dn_s[tid] = (float)(1.0 / sqrt((double)deg_s[tid] + 1e-8));
        __syncthreads();
        {   // arow = adj * dn_i * dn_j  (adj = own-block wpli, L1/L2 hit)
            int i = tid >> 4, j4 = tid & 15;
            float4 v = *(const float4*)&wpli[b * 4096 + i * 64 + j4 * 4];
            float di = dn_s[i];
            v.x *= di * dn_s[j4 * 4 + 0];
            v.y *= di * dn_s[j4 * 4 + 1];
            v.z *= di * dn_s[j4 * 4 + 2];
            v.w *= di * dn_s[j4 * 4 + 3];
            *(float4*)&arow[i * 68 + j4 * 4] = v;
        }
        #pragma unroll
        for (int p = 0; p < 2; ++p) {            // stage eeg
            int idx4 = tid + p * 1024;
            int r = idx4 >> 5, c4 = idx4 & 31;
            *(float4*)&xs[r * 128 + c4 * 4] = ((const float4*)(eeg + b * 8192))[idx4];
        }
        #pragma unroll
        for (int p = 0; p < 4; ++p) {            // stage W1^T [k][o]
            int idx4 = tid + p * 1024;
            int o = idx4 & 127, k4 = idx4 >> 7;
            float4 w = *(const float4*)&g1w[o * 128 + k4 * 4];
            WsT[(k4 * 4 + 0) * 128 + o] = w.x;
            WsT[(k4 * 4 + 1) * 128 + o] = w.y;
            WsT[(k4 * 4 + 2) * 128 + o] = w.z;
            WsT[(k4 * 4 + 3) * 128 + o] = w.w;
        }
        __syncthreads();
        int i = tid >> 4;
        {   // support
            int f0 = (tid & 15) * 8;
            float a0 = 0.f, a1 = 0.f, a2 = 0.f, a3 = 0.f,
                  a4 = 0.f, a5 = 0.f, a6 = 0.f, a7 = 0.f;
            #pragma unroll 8
            for (int j = 0; j < 64; ++j) {
                float a = arow[i * 68 + j];
                float4 x0 = *(const float4*)&xs[j * 128 + f0];
                float4 x1v = *(const float4*)&xs[j * 128 + f0 + 4];
                a0 += a * x0.x; a1 += a * x0.y; a2 += a * x0.z; a3 += a * x0.w;
                a4 += a * x1v.x; a5 += a * x1v.y; a6 += a * x1v.z; a7 += a * x1v.w;
            }
            *(float4*)&sup[i * 128 + f0]     = make_float4(a0, a1, a2, a3);
            *(float4*)&sup[i * 128 + f0 + 4] = make_float4(a4, a5, a6, a7);
        }
        __syncthreads();
        {   // linear OUT=128 + x1 global + BN1 partials
            int o0 = (tid & 15) * 8;
            float c[8] = {};
            #pragma unroll 8
            for (int k = 0; k < 128; ++k) {
                float s = sup[i * 128 + k];
                float4 w0 = *(const float4*)&WsT[k * 128 + o0];
                float4 w1 = *(const float4*)&WsT[k * 128 + o0 + 4];
                c[0] += s * w0.x; c[1] += s * w0.y; c[2] += s * w0.z; c[3] += s * w0.w;
                c[4] += s * w1.x; c[5] += s * w1.y; c[6] += s * w1.z; c[7] += s * w1.w;
            }
            float4 r0 = make_float4(c[0] + g1b[o0], c[1] + g1b[o0 + 1],
                                    c[2] + g1b[o0 + 2], c[3] + g1b[o0 + 3]);
            float4 r1 = make_float4(c[4] + g1b[o0 + 4], c[5] + g1b[o0 + 5],
                                    c[6] + g1b[o0 + 6], c[7] + g1b[o0 + 7]);
            *(float4*)&w_x1[b * 8192 + i * 128 + o0]     = r0;
            *(float4*)&w_x1[b * 8192 + i * 128 + o0 + 4] = r1;
            double ds  = (double)r0.x + (double)r0.y + (double)r0.z + (double)r0.w
                       + (double)r1.x + (double)r1.y + (double)r1.z + (double)r1.w;
            double ds2 = (double)r0.x * r0.x + (double)r0.y * r0.y
                       + (double)r0.z * r0.z + (double)r0.w * r0.w
                       + (double)r1.x * r1.x + (double)r1.y * r1.y
                       + (double)r1.z * r1.z + (double)r1.w * r1.w;
            #pragma unroll
            for (int off = 8; off > 0; off >>= 1) {
                ds  += __shfl_down(ds, off, 16);
                ds2 += __shfl_down(ds2, off, 16);
            }
            if ((tid & 15) == 0) {
                dpart1[(b * 64 + i) * 2]     = ds;
                dpart1[(b * 64 + i) * 2 + 1] = ds2;
            }
        }
    }
    grid_bar(&bar[0], NBLK);

    // ===================== PHASE G2: GCN layer 2 =====================
    {
        float* xs   = (float*)(U);               // [64][128] BN1(x1)
        float* WsT  = (float*)(U + 32768);       // [128][64] 32 KB
        float* x2_s = (float*)(U + 65536);       // [64][64] 16 KB (persists to attn)
        float* sup  = (float*)(U + 98304);       // [64][128]
        double* dred = (double*)(U + 98304);     // temp reuse for stat reduce
        {   // parallel BN1 stat partial reduce (16 chunks x 64 ch)
            int c = tid & 63, chunk = tid >> 6;
            double s = 0.0, s2 = 0.0;
            for (int bi = chunk * 8; bi < chunk * 8 + 8; ++bi) {
                s  += dpart1[(bi * 64 + c) * 2];
                s2 += dpart1[(bi * 64 + c) * 2 + 1];
            }
            dred[(chunk * 64 + c) * 2]     = s;
            dred[(chunk * 64 + c) * 2 + 1] = s2;
        }
        __syncthreads();
        if (tid < 64) {
            double s = 0.0, s2 = 0.0;
            for (int ch = 0; ch < 16; ++ch) {
                s  += dred[(ch * 64 + tid) * 2];
                s2 += dred[(ch * 64 + tid) * 2 + 1];
            }
            double N = (double)(NB * HIDN);
            double m = s / N;
            double var = s2 / N - m * m;
            stat_s[tid * 2]     = (float)m;
            stat_s[tid * 2 + 1] = (float)(1.0 / sqrt(var + 1e-5));
        }
        __syncthreads();
        #pragma unroll
        for (int p = 0; p < 2; ++p) {            // stage BN1+ReLU(x1)
            int idx4 = tid + p * 1024;
            int r = idx4 >> 5, c4 = idx4 & 31;
            float4 v = ((const float4*)(w_x1 + b * 8192))[idx4];
            float m = stat_s[r * 2], rs = stat_s[r * 2 + 1], gg = bn1g[r], bv = bn1b[r];
            v.x = (v.x - m) * rs * gg + bv; v.x = v.x > 0.f ? v.x : 0.f;
            v.y = (v.y - m) * rs * gg + bv; v.y = v.y > 0.f ? v.y : 0.f;
            v.z = (v.z - m) * rs * gg + bv; v.z = v.z > 0.f ? v.z : 0.f;
            v.w = (v.w - m) * rs * gg + bv; v.w = v.w > 0.f ? v.w : 0.f;
            *(float4*)&xs[r * 128 + c4 * 4] = v;
        }
        #pragma unroll
        for (int p = 0; p < 2; ++p) {            // stage W2^T [k][o]
            int idx4 = tid + p * 1024;
            int o = idx4 & 63, k4 = idx4 >> 6;
            float4 w = *(const float4*)&g2w[o * 128 + k4 * 4];
            WsT[(k4 * 4 + 0) * 64 + o] = w.x;
            WsT[(k4 * 4 + 1) * 64 + o] = w.y;
            WsT[(k4 * 4 + 2) * 64 + o] = w.z;
            WsT[(k4 * 4 + 3) * 64 + o] = w.w;
        }
        __syncthreads();
        int i = tid >> 4;
        {   // support
            int f0 = (tid & 15) * 8;
            float a0 = 0.f, a1 = 0.f, a2 = 0.f, a3 = 0.f,
                  a4 = 0.f, a5 = 0.f, a6 = 0.f, a7 = 0.f;
            #pragma unroll 8
            for (int j = 0; j < 64; ++j) {
                float a = arow[i * 68 + j];
                float4 x0 = *(const float4*)&xs[j * 128 + f0];
                float4 x1v = *(const float4*)&xs[j * 128 + f0 + 4];
                a0 += a * x0.x; a1 += a * x0.y; a2 += a * x0.z; a3 += a * x0.w;
                a4 += a * x1v.x; a5 += a * x1v.y; a6 += a * x1v.z; a7 += a * x1v.w;
            }
            *(float4*)&sup[i * 128 + f0]     = make_float4(a0, a1, a2, a3);
            *(float4*)&sup[i * 128 + f0 + 4] = make_float4(a4, a5, a6, a7);
        }
        __syncthreads();
        {   // linear OUT=64 -> x2 in LDS + BN2 partials
            int o0 = (tid & 15) * 4;
            float c[4] = {};
            #pragma unroll 8
            for (int k = 0; k < 128; ++k) {
                float s = sup[i * 128 + k];
                float4 w0 = *(const float4*)&WsT[k * 64 + o0];
                c[0] += s * w0.x; c[1] += s * w0.y; c[2] += s * w0.z; c[3] += s * w0.w;
            }
            float4 r0 = make_float4(c[0] + g2b[o0], c[1] + g2b[o0 + 1],
                                    c[2] + g2b[o0 + 2], c[3] + g2b[o0 + 3]);
            *(float4*)&x2_s[i * 64 + o0] = r0;
            double ds  = (double)r0.x + (double)r0.y + (double)r0.z + (double)r0.w;
            double ds2 = (double)r0.x * r0.x + (double)r0.y * r0.y
                       + (double)r0.z * r0.z + (double)r0.w * r0.w;
            #pragma unroll
            for (int off = 8; off > 0; off >>= 1) {
                ds  += __shfl_down(ds, off, 16);
                ds2 += __shfl_down(ds2, off, 16);
            }
            if ((tid & 15) == 0) {
                dpart2[(b * 64 + i) * 2]     = ds;
                dpart2[(b * 64 + i) * 2 + 1] = ds2;
            }
        }
    }
    grid_bar(&bar[1], NBLK);

    // ===================== PHASE A: attention + pool + proj =====================
    {
        float* xs2    = (float*)(U);             // [64][68] 17.4 KB
        float* ws     = (float*)(U + 32768);     // [192][64] 48 KB (Win)
        float* x2_s   = (float*)(U + 65536);     // [64][64] from G2
        float* kqkv   = (float*)(U + 81920);     // [192][64] 48 KB
        double* dred  = (double*)(U + 81920);    // temp (before kqkv used)
        float* pm_s   = (float*)(U + 32768);     // overlays ws after QKV
        float* ps_s   = (float*)(U + 36864);
        float* pool_s = (float*)(U + 40960);     // [64][17]
        float* mo     = (float*)(U + 45440);     // [64]
        {   // parallel BN2 stat reduce
            int c = tid & 63, chunk = tid >> 6;
            double s = 0.0, s2 = 0.0;
            for (int bi = chunk * 8; bi < chunk * 8 + 8; ++bi) {
                s  += dpart2[(bi * 64 + c) * 2];
                s2 += dpart2[(bi * 64 + c) * 2 + 1];
            }
            dred[(chunk * 64 + c) * 2]     = s;
            dred[(chunk * 64 + c) * 2 + 1] = s2;
        }
        __syncthreads();
        if (tid < 64) {
            double s = 0.0, s2 = 0.0;
            for (int ch = 0; ch < 16; ++ch) {
                s  += dred[(ch * 64 + tid) * 2];
                s2 += dred[(ch * 64 + tid) * 2 + 1];
            }
            double N = (double)(NB * NE);
            double m = s / N;
            double var = s2 / N - m * m;
            stat_s[tid * 2]     = (float)m;
            stat_s[tid * 2 + 1] = (float)(1.0 / sqrt(var + 1e-5));
        }
        __syncthreads();
        {   // xs2 = BN2+ReLU(x2) from LDS
            int r = tid >> 4, c4 = tid & 15;
            float4 v = *(const float4*)&x2_s[r * 64 + c4 * 4];
            float m = stat_s[r * 2], rs = stat_s[r * 2 + 1], gg = bn2g[r], bv = bn2b[r];
            v.x = (v.x - m) * rs * gg + bv; v.x = v.x > 0.f ? v.x : 0.f;
            v.y = (v.y - m) * rs * gg + bv; v.y = v.y > 0.f ? v.y : 0.f;
            v.z = (v.z - m) * rs * gg + bv; v.z = v.z > 0.f ? v.z : 0.f;
            v.w = (v.w - m) * rs * gg + bv; v.w = v.w > 0.f ? v.w : 0.f;
            *(float4*)&xs2[r * 68 + c4 * 4] = v;
        }
        __syncthreads();                          // x2_s dead; stage Win over [32K,80K)
        #pragma unroll
        for (int p = 0; p < 3; ++p) {
            int idx4 = tid + p * 1024;
            int o = idx4 >> 4, c4 = idx4 & 15;
            *(float4*)&ws[o * 64 + c4 * 4] = ((const float4*)(wiw + o * 64))[c4];
        }
        __syncthreads();
        // QKV: thread (lane=n, wv) -> 12 outputs o = wv + 16u
        float acc[12];
        #pragma unroll
        for (int u = 0; u < 12; ++u) acc[u] = wib[wv + 16 * u];
        #pragma unroll
        for (int d4 = 0; d4 < 16; ++d4) {
            float4 xv = *(const float4*)&xs2[lane * 68 + d4 * 4];
            #pragma unroll
            for (int u = 0; u < 12; ++u) {
                float4 w = *(const float4*)&ws[(wv + 16 * u) * 64 + d4 * 4];
                acc[u] += xv.x * w.x + xv.y * w.y + xv.z * w.z + xv.w * w.w;
            }
        }
        #pragma unroll
        for (int u = 0; u < 12; ++u) kqkv[(wv + 16 * u) * 64 + lane] = acc[u];
        __syncthreads();
        // scores: thread (h, jc, n=lane), 16 keys
        int h = wv >> 2, jc = wv & 3;
        int e0 = 16 * h, j0 = jc * 16, hn = h * 64 + lane;
        float q[16];
        #pragma unroll
        for (int d = 0; d < 16; ++d) q[d] = kqkv[(e0 + d) * 64 + lane];
        float sc[16];
        #pragma unroll
        for (int jj = 0; jj < 16; ++jj) sc[jj] = 0.f;
        #pragma unroll
        for (int d = 0; d < 16; ++d) {
            float qd = q[d];
            #pragma unroll
            for (int j4 = 0; j4 < 4; ++j4) {
                float4 kv = *(const float4*)&kqkv[(64 + e0 + d) * 64 + j0 + j4 * 4];
                sc[j4 * 4 + 0] += qd * kv.x;
                sc[j4 * 4 + 1] += qd * kv.y;
                sc[j4 * 4 + 2] += qd * kv.z;
                sc[j4 * 4 + 3] += qd * kv.w;
            }
        }
        float pmax = -1e30f;
        #pragma unroll
        for (int jj = 0; jj < 16; ++jj) { sc[jj] *= 0.25f; pmax = fmaxf(pmax, sc[jj]); }
        pm_s[jc * 256 + hn] = pmax;
        __syncthreads();
        float mx = fmaxf(fmaxf(pm_s[0 * 256 + hn], pm_s[1 * 256 + hn]),
                         fmaxf(pm_s[2 * 256 + hn], pm_s[3 * 256 + hn]));
        float psum = 0.f;
        #pragma unroll
        for (int jj = 0; jj < 16; ++jj) { sc[jj] = expf(sc[jj] - mx); psum += sc[jj]; }
        ps_s[jc * 256 + hn] = psum;
        float po[16];
        #pragma unroll
        for (int d = 0; d < 16; ++d) {
            float4 v0 = *(const float4*)&kqkv[(128 + e0 + d) * 64 + j0 + 0];
            float4 v1 = *(const float4*)&kqkv[(128 + e0 + d) * 64 + j0 + 4];
            float4 v2 = *(const float4*)&kqkv[(128 + e0 + d) * 64 + j0 + 8];
            float4 v3 = *(const float4*)&kqkv[(128 + e0 + d) * 64 + j0 + 12];
            po[d] = sc[0] * v0.x + sc[1] * v0.y + sc[2] * v0.z + sc[3] * v0.w
                  + sc[4] * v1.x + sc[5] * v1.y + sc[6] * v1.z + sc[7] * v1.w
                  + sc[8] * v2.x + sc[9] * v2.y + sc[10] * v2.z + sc[11] * v2.w
                  + sc[12] * v3.x + sc[13] * v3.y + sc[14] * v3.z + sc[15] * v3.w;
        }
        __syncthreads();
        float inv = 1.f / (ps_s[0 * 256 + hn] + ps_s[1 * 256 + hn]
                         + ps_s[2 * 256 + hn] + ps_s[3 * 256 + hn]);
        if (jc == 0) {
            #pragma unroll
            for (int d = 0; d < 16; ++d) kqkv[(e0 + d) * 64 + lane] = po[d];
        }
        __syncthreads();
        if (jc == 1) {
            #pragma unroll
            for (int d = 0; d < 16; ++d) kqkv[(e0 + d) * 64 + lane] += po[d];
        }
        __syncthreads();
        if (jc == 2) {
            #pragma unroll
            for (int d = 0; d < 16; ++d) kqkv[(e0 + d) * 64 + lane] += po[d];
        }
        __syncthreads();
        if (jc == 3) {
            #pragma unroll
            for (int d = 0; d < 16; ++d)
                kqkv[(e0 + d) * 64 + lane] = (kqkv[(e0 + d) * 64 + lane] + po[d]) * inv;
        }
        __syncthreads();
        {   // pool over n
            int e = tid >> 4, part = tid & 15;
            float4 v = *(const float4*)&kqkv[e * 64 + part * 4];
            pool_s[e * 17 + part] = v.x + v.y + v.z + v.w;
        }
        __syncthreads();
        if (tid < 64) {
            float s = 0.f;
            #pragma unroll
            for (int p = 0; p < 16; ++p) s += pool_s[tid * 17 + p];
            mo[tid] = s * (1.f / 64.f);
        }
        __syncthreads();
        if (tid < 64) {
            float a = wob[tid];
            const float4* wr = (const float4*)(wow + tid * 64);
            #pragma unroll
            for (int d4 = 0; d4 < 16; ++d4) {
                float4 w = wr[d4];
                a += mo[d4 * 4 + 0] * w.x + mo[d4 * 4 + 1] * w.y
                   + mo[d4 * 4 + 2] * w.z + mo[d4 * 4 + 3] * w.w;
            }
            feat[b * NE + tid] = a;
        }
    }
}

// ---------------------------------------------------------------------------
extern "C" void kernel_launch(void* const* d_in, const int* in_sizes, int n_in,
                              void* d_out, int out_size, void* d_ws, size_t ws_size,
                              hipStream_t stream) {
    const float* eeg      = (const float*)d_in[0];
    const float* gcn1_w   = (const float*)d_in[1];
    const float* gcn1_b   = (const float*)d_in[2];
    const float* gcn2_w   = (const float*)d_in[3];
    const float* gcn2_b   = (const float*)d_in[4];
    const float* bn1_g    = (const float*)d_in[5];
    const float* bn1_b    = (const float*)d_in[6];
    const float* bn2_g    = (const float*)d_in[7];
    const float* bn2_b    = (const float*)d_in[8];
    const float* attn_in_w  = (const float*)d_in[9];
    const float* attn_in_b  = (const float*)d_in[10];
    const float* attn_out_w = (const float*)d_in[11];
    const float* attn_out_b = (const float*)d_in[12];

    float* out  = (float*)d_out;
    float* feat = out;                          // [B, E]
    float* wpli = out + NB * NE;                // [B, C, C]

    float* ws = (float*)d_ws;
    float*  w_re   = ws;                        // [1M]
    float*  w_im   = ws + 1048576;              // [1M]
    float*  w_x1   = ws + 2097152;              // [1M]
    double* dpart1 = (double*)(ws + 3145728);   // [128*64*2]
    double* dpart2 = (double*)(ws + 3178496);   // [128*64*2]
    int*    bar    = (int*)(ws + 3211264);      // [16]

    // reset grid barriers (graph-capturable)
    hipMemsetAsync(bar, 0, 64, stream);
    // 1. analytic signal (bit-identical, full-GPU)
    analytic_kernel<<<NB * NC, NT, 0, stream>>>(eeg, w_re, w_im);
    // 2. everything else in one resident kernel with 2 grid barriers
    mega_kernel<<<NBLK, 1024, 0, stream>>>(
        eeg, w_re, w_im, gcn1_w, gcn1_b, gcn2_w, gcn2_b,
        bn1_g, bn1_b, bn2_g, bn2_b, attn_in_w, attn_in_b,
        attn_out_w, attn_out_b, wpli, feat, w_x1, dpart1, dpart2, bar);
}

// Round 9
// 103.245 us; speedup vs baseline: 2.6397x; 2.6397x over previous
//
#include <hip/hip_runtime.h>
#include <math.h>

#define NB 128     // batch
#define NC 64      // channels
#define NT 128     // segment length
#define HIDN 128   // hidden
#define NE 64      // attn embed
#define NHD 4      // heads
#define HD 16      // head dim

// ---------------------------------------------------------------------------
// 1. Analytic signal (unchanged; bit-identical math; [b][c][t] layout).
// ---------------------------------------------------------------------------
__global__ void analytic_kernel(const float* __restrict__ eeg,
                                float* __restrict__ re, float* __restrict__ im) {
    int row = blockIdx.x;            // b*NC + c
    int t = threadIdx.x;             // 0..127
    __shared__ float xs[NT];
    __shared__ double cotv[64];
    xs[t] = eeg[row * NT + t];
    if (t < 64) {
        double d = (double)(2 * t + 1);
        double a = 3.14159265358979323846 * d / 128.0;
        cotv[t] = cos(a) / sin(a);
    }
    __syncthreads();
    double ar = 0.0, ai = 0.0;
    #pragma unroll
    for (int m = 0; m < 64; ++m) {
        int d = 2 * m + 1;
        int s = (t - d) & 127;
        double xv = (double)xs[s];
        ar += xv;
        ai += cotv[m] * xv;
    }
    double rr = (double)xs[t] + ar * (1.0 / 64.0);
    double ii = ai * (1.0 / 64.0);
    re[row * NT + t] = (float)rr;
    im[row * NT + t] = (float)ii;
}

// ---------------------------------------------------------------------------
// 2. PLI v3 (unchanged from R6/R7). Bit-identical accumulation.
// ---------------------------------------------------------------------------
__global__ void pli_kernel(const float* __restrict__ re, const float* __restrict__ im,
                           float* __restrict__ wpli, float* __restrict__ deg) {
    int b = blockIdx.x >> 4;
    int i0 = (blockIdx.x & 15) << 2;
    int tid = threadIdx.x;           // 256
    int w = tid >> 6;
    int j = tid & 63;
    __shared__ float4 sre4[64 * 32];
    __shared__ float4 sim4[64 * 32];
    __shared__ int pacc[4][4][64];
    const float* reb = re + b * (NC * NT);
    const float* imb = im + b * (NC * NT);
    for (int idx4 = tid; idx4 < 2048; idx4 += 256) {
        int c = idx4 >> 5, t4 = idx4 & 31;
        int slot = c * 32 + (t4 ^ (c & 31));
        sre4[slot] = ((const float4*)reb)[idx4];
        sim4[slot] = ((const float4*)imb)[idx4];
    }
    __syncthreads();
    int acc0 = 0, acc1 = 0, acc2 = 0, acc3 = 0;
    #pragma unroll
    for (int tt = 0; tt < 8; ++tt) {
        int t4 = w * 8 + tt;
        float4 rj = sre4[j * 32 + (t4 ^ (j & 31))];
        float4 ij = sim4[j * 32 + (t4 ^ (j & 31))];
        #pragma unroll
        for (int di = 0; di < 4; ++di) {
            int i = i0 + di;
            float4 ri = sre4[i * 32 + (t4 ^ (i & 31))];
            float4 ii = sim4[i * 32 + (t4 ^ (i & 31))];
            float c0 = ii.x * rj.x - ri.x * ij.x;
            float c1 = ii.y * rj.y - ri.y * ij.y;
            float c2 = ii.z * rj.z - ri.z * ij.z;
            float c3 = ii.w * rj.w - ri.w * ij.w;
            int d = ((c0 > 0.f) ? 1 : ((c0 < 0.f) ? -1 : 0))
                  + ((c1 > 0.f) ? 1 : ((c1 < 0.f) ? -1 : 0))
                  + ((c2 > 0.f) ? 1 : ((c2 < 0.f) ? -1 : 0))
                  + ((c3 > 0.f) ? 1 : ((c3 < 0.f) ? -1 : 0));
            if (di == 0) acc0 += d;
            else if (di == 1) acc1 += d;
            else if (di == 2) acc2 += d;
            else acc3 += d;
        }
    }
    pacc[w][0][j] = acc0; pacc[w][1][j] = acc1;
    pacc[w][2][j] = acc2; pacc[w][3][j] = acc3;
    __syncthreads();
    int di2 = tid >> 6, j2 = tid & 63;
    int a = pacc[0][di2][j2] + pacc[1][di2][j2] + pacc[2][di2][j2] + pacc[3][di2][j2];
    float p = fabsf((float)a * (1.f / (float)NT));
    int i = i0 + di2;
    if (j2 == i) p = 0.f;
    wpli[b * (NC * NC) + i * NC + j2] = p;
    float s = p;
    #pragma unroll
    for (int off = 32; off > 0; off >>= 1) s += __shfl_down(s, off);
    if (j2 == 0) deg[b * NC + i] = s;
}

// ---------------------------------------------------------------------------
// 3. Fused GCN layer, 2 blocks per batch (grid 256 = all CUs busy).
//    Block (b, half): stages full A_n/x/W, computes rows i in
//    [half*32, half*32+32). BN partial reduce parallelized 16-way.
// ---------------------------------------------------------------------------
template <int OUT, bool BN_IN>
__global__ __launch_bounds__(1024, 1) void gcn_fused(
        const float* __restrict__ adj, const float* __restrict__ deg,
        const float* __restrict__ x, const double* __restrict__ dpart_in,
        const float* __restrict__ g, const float* __restrict__ bb,
        const float* __restrict__ W, const float* __restrict__ bias,
        float* __restrict__ xout, double* __restrict__ dpart_out) {
    int b = blockIdx.x >> 1;
    int half = blockIdx.x & 1;
    int tid = threadIdx.x;           // 1024
    __shared__ float dn_s[64];
    __shared__ float stat_s[64][2];
    __shared__ float arow[32][68];
    __shared__ float xs[64][128];
    __shared__ float sup[32][132];
    __shared__ float WsT[128][(OUT == 128) ? 132 : 68];  // [k][o]
    __shared__ double dred[16][64][2];

    if (BN_IN) {                     // 16-way parallel partial reduce
        int c = tid & 63, chunk = tid >> 6;
        double s = 0.0, s2 = 0.0;
        for (int bi = chunk * 8; bi < chunk * 8 + 8; ++bi) {
            s  += dpart_in[(bi * 64 + c) * 2];
            s2 += dpart_in[(bi * 64 + c) * 2 + 1];
        }
        dred[chunk][c][0] = s;
        dred[chunk][c][1] = s2;
    }
    if (tid < 64)
        dn_s[tid] = (float)(1.0 / sqrt((double)deg[b * 64 + tid] + 1e-8));
    __syncthreads();
    if (BN_IN && tid < 64) {
        double s = 0.0, s2 = 0.0;
        for (int ch = 0; ch < 16; ++ch) {
            s  += dred[ch][tid][0];
            s2 += dred[ch][tid][1];
        }
        double N = (double)(NB * HIDN);
        double m = s / N;
        double var = s2 / N - m * m;
        stat_s[tid][0] = (float)m;
        stat_s[tid][1] = (float)(1.0 / sqrt(var + 1e-5));
    }
    __syncthreads();
    // stage arow (this half's 32 rows)
    if (tid < 512) {
        int il = tid >> 4, j4 = tid & 15;
        int i = half * 32 + il;
        float4 v = *(const float4*)&adj[b * 4096 + i * 64 + j4 * 4];
        float di = dn_s[i];
        v.x *= di * dn_s[j4 * 4 + 0];
        v.y *= di * dn_s[j4 * 4 + 1];
        v.z *= di * dn_s[j4 * 4 + 2];
        v.w *= di * dn_s[j4 * 4 + 3];
        *(float4*)&arow[il][j4 * 4] = v;
    }
    // stage xs (full 64 x 128; BN+ReLU for layer 2)
    #pragma unroll
    for (int p = 0; p < 2; ++p) {
        int idx4 = tid + p * 1024;
        int r = idx4 >> 5, c4 = idx4 & 31;
        float4 v = ((const float4*)(x + b * 8192))[idx4];
        if (BN_IN) {
            float m = stat_s[r][0], rs = stat_s[r][1], gg = g[r], bv = bb[r];
            v.x = (v.x - m) * rs * gg + bv; v.x = v.x > 0.f ? v.x : 0.f;
            v.y = (v.y - m) * rs * gg + bv; v.y = v.y > 0.f ? v.y : 0.f;
            v.z = (v.z - m) * rs * gg + bv; v.z = v.z > 0.f ? v.z : 0.f;
            v.w = (v.w - m) * rs * gg + bv; v.w = v.w > 0.f ? v.w : 0.f;
        }
        *(float4*)&xs[r][c4 * 4] = v;
    }
    // stage W transposed [k][o]
    #pragma unroll
    for (int p = 0; p < OUT / 32; ++p) {
        int idx4 = tid + p * 1024;
        int o = idx4 & (OUT - 1);
        int k4 = idx4 / OUT;
        float4 w = *(const float4*)&W[o * 128 + k4 * 4];
        WsT[k4 * 4 + 0][o] = w.x;
        WsT[k4 * 4 + 1][o] = w.y;
        WsT[k4 * 4 + 2][o] = w.z;
        WsT[k4 * 4 + 3][o] = w.w;
    }
    __syncthreads();

    // --- phase 1: support (32 rows x 128 cols; thread = (il, 4 cols)) ---
    int il = tid >> 5;
    int i = half * 32 + il;
    {
        int f0 = (tid & 31) * 4;
        float a0 = 0.f, a1 = 0.f, a2 = 0.f, a3 = 0.f;
        #pragma unroll 8
        for (int j = 0; j < 64; ++j) {
            float a = arow[il][j];
            float4 xv = *(const float4*)&xs[j][f0];
            a0 += a * xv.x; a1 += a * xv.y; a2 += a * xv.z; a3 += a * xv.w;
        }
        *(float4*)&sup[il][f0] = make_float4(a0, a1, a2, a3);
    }
    __syncthreads();

    // --- phase 2: linear + BN partials ---
    double ds = 0.0, ds2 = 0.0;
    if (OUT == 128) {
        int o0 = (tid & 31) * 4;
        float c[4] = {};
        #pragma unroll 8
        for (int k = 0; k < 128; ++k) {
            float s = sup[il][k];
            float4 w0 = *(const float4*)&WsT[k][o0];
            c[0] += s * w0.x; c[1] += s * w0.y; c[2] += s * w0.z; c[3] += s * w0.w;
        }
        float4 r0 = make_float4(c[0] + bias[o0], c[1] + bias[o0 + 1],
                                c[2] + bias[o0 + 2], c[3] + bias[o0 + 3]);
        *(float4*)&xout[b * 64 * 128 + i * 128 + o0] = r0;
        ds  = (double)r0.x + (double)r0.y + (double)r0.z + (double)r0.w;
        ds2 = (double)r0.x * r0.x + (double)r0.y * r0.y
            + (double)r0.z * r0.z + (double)r0.w * r0.w;
    } else {
        int o0 = (tid & 31) * 2;
        float c0 = 0.f, c1 = 0.f;
        #pragma unroll 8
        for (int k = 0; k < 128; ++k) {
            float s = sup[il][k];
            c0 += s * WsT[k][o0];
            c1 += s * WsT[k][o0 + 1];
        }
        c0 += bias[o0];
        c1 += bias[o0 + 1];
        *(float2*)&xout[b * 64 * 64 + i * 64 + o0] = make_float2(c0, c1);
        ds  = (double)c0 + (double)c1;
        ds2 = (double)c0 * c0 + (double)c1 * c1;
    }
    // reduce across the 32 threads of row i (lanes tid&31)
    #pragma unroll
    for (int off = 16; off > 0; off >>= 1) {
        ds  += __shfl_down(ds, off, 32);
        ds2 += __shfl_down(ds2, off, 32);
    }
    if ((tid & 31) == 0) {
        dpart_out[(b * 64 + i) * 2]     = ds;
        dpart_out[(b * 64 + i) * 2 + 1] = ds2;
    }
}

// ---------------------------------------------------------------------------
// 4. Attention v5 (unchanged from R7): per-batch block, 1024 threads.
// ---------------------------------------------------------------------------
__global__ __launch_bounds__(1024, 1) void attn_fused(
        const float* __restrict__ x2, const double* __restrict__ dpart2,
        const float* __restrict__ g, const float* __restrict__ bb,
        const float* __restrict__ Win, const float* __restrict__ bin,
        const float* __restrict__ Wout, const float* __restrict__ bout,
        float* __restrict__ feat) {
    int b = blockIdx.x;
    int tid = threadIdx.x;
    int lane = tid & 63, wv = tid >> 6;
    __shared__ float stat_s[64][2];
    __shared__ float xs[64][68];
    __shared__ float ws[192][64];
    __shared__ float kqkv[192][64];
    __shared__ float pm_s[4][256], ps_s[4][256];
    __shared__ float pool_s[64][17];
    __shared__ float mo[64];

    if (tid < 64) {
        double s = 0.0, s2 = 0.0;
        for (int bi = 0; bi < NB; ++bi) {
            s  += dpart2[(bi * 64 + tid) * 2];
            s2 += dpart2[(bi * 64 + tid) * 2 + 1];
        }
        double N = (double)(NB * NE);
        double m = s / N;
        double var = s2 / N - m * m;
        stat_s[tid][0] = (float)m;
        stat_s[tid][1] = (float)(1.0 / sqrt(var + 1e-5));
    }
    #pragma unroll
    for (int p = 0; p < 3; ++p) {
        int idx4 = tid + p * 1024;
        int o = idx4 >> 4, c4 = idx4 & 15;
        *(float4*)&ws[o][c4 * 4] = ((const float4*)(Win + o * 64))[c4];
    }
    __syncthreads();
    {
        int r = tid >> 4, c4 = tid & 15;
        float4 v = ((const float4*)(x2 + b * 4096))[tid];
        float m = stat_s[r][0], rs = stat_s[r][1], gg = g[r], bv = bb[r];
        v.x = (v.x - m) * rs * gg + bv; v.x = v.x > 0.f ? v.x : 0.f;
        v.y = (v.y - m) * rs * gg + bv; v.y = v.y > 0.f ? v.y : 0.f;
        v.z = (v.z - m) * rs * gg + bv; v.z = v.z > 0.f ? v.z : 0.f;
        v.w = (v.w - m) * rs * gg + bv; v.w = v.w > 0.f ? v.w : 0.f;
        *(float4*)&xs[r][c4 * 4] = v;
    }
    __syncthreads();

    float xr[64];
    #pragma unroll
    for (int d4 = 0; d4 < 16; ++d4) {
        float4 v = *(const float4*)&xs[lane][d4 * 4];
        xr[d4 * 4 + 0] = v.x; xr[d4 * 4 + 1] = v.y;
        xr[d4 * 4 + 2] = v.z; xr[d4 * 4 + 3] = v.w;
    }
    float acc[12];
    #pragma unroll
    for (int u = 0; u < 12; ++u) acc[u] = bin[wv + 16 * u];
    #pragma unroll
    for (int d4 = 0; d4 < 16; ++d4) {
        #pragma unroll
        for (int u = 0; u < 12; ++u) {
            float4 w = *(const float4*)&ws[wv + 16 * u][d4 * 4];
            acc[u] += xr[d4 * 4 + 0] * w.x + xr[d4 * 4 + 1] * w.y
                    + xr[d4 * 4 + 2] * w.z + xr[d4 * 4 + 3] * w.w;
        }
    }
    #pragma unroll
    for (int u = 0; u < 12; ++u) kqkv[wv + 16 * u][lane] = acc[u];
    __syncthreads();

    int h = wv >> 2, jc = wv & 3;
    int e0 = 16 * h, j0 = jc * 16, hn = h * 64 + lane;
    float q[16];
    #pragma unroll
    for (int d = 0; d < 16; ++d) q[d] = kqkv[e0 + d][lane];
    float sc[16];
    #pragma unroll
    for (int jj = 0; jj < 16; ++jj) sc[jj] = 0.f;
    #pragma unroll
    for (int d = 0; d < 16; ++d) {
        float qd = q[d];
        #pragma unroll
        for (int j4 = 0; j4 < 4; ++j4) {
            float4 kv = *(const float4*)&kqkv[64 + e0 + d][j0 + j4 * 4];
            sc[j4 * 4 + 0] += qd * kv.x;
            sc[j4 * 4 + 1] += qd * kv.y;
            sc[j4 * 4 + 2] += qd * kv.z;
            sc[j4 * 4 + 3] += qd * kv.w;
        }
    }
    float pmax = -1e30f;
    #pragma unroll
    for (int jj = 0; jj < 16; ++jj) { sc[jj] *= 0.25f; pmax = fmaxf(pmax, sc[jj]); }
    pm_s[jc][hn] = pmax;
    __syncthreads();
    float mx = fmaxf(fmaxf(pm_s[0][hn], pm_s[1][hn]),
                     fmaxf(pm_s[2][hn], pm_s[3][hn]));
    float psum = 0.f;
    #pragma unroll
    for (int jj = 0; jj < 16; ++jj) { sc[jj] = expf(sc[jj] - mx); psum += sc[jj]; }
    ps_s[jc][hn] = psum;
    float po[16];
    #pragma unroll
    for (int d = 0; d < 16; ++d) {
        float4 v0 = *(const float4*)&kqkv[128 + e0 + d][j0 + 0];
        float4 v1 = *(const float4*)&kqkv[128 + e0 + d][j0 + 4];
        float4 v2 = *(const float4*)&kqkv[128 + e0 + d][j0 + 8];
        float4 v3 = *(const float4*)&kqkv[128 + e0 + d][j0 + 12];
        po[d] = sc[0] * v0.x + sc[1] * v0.y + sc[2] * v0.z + sc[3] * v0.w
              + sc[4] * v1.x + sc[5] * v1.y + sc[6] * v1.z + sc[7] * v1.w
              + sc[8] * v2.x + sc[9] * v2.y + sc[10] * v2.z + sc[11] * v2.w
              + sc[12] * v3.x + sc[13] * v3.y + sc[14] * v3.z + sc[15] * v3.w;
    }
    __syncthreads();
    float inv = 1.f / (ps_s[0][hn] + ps_s[1][hn] + ps_s[2][hn] + ps_s[3][hn]);
    if (jc == 0) {
        #pragma unroll
        for (int d = 0; d < 16; ++d) kqkv[e0 + d][lane] = po[d];
    }
    __syncthreads();
    if (jc == 1) {
        #pragma unroll
        for (int d = 0; d < 16; ++d) kqkv[e0 + d][lane] += po[d];
    }
    __syncthreads();
    if (jc == 2) {
        #pragma unroll
        for (int d = 0; d < 16; ++d) kqkv[e0 + d][lane] += po[d];
    }
    __syncthreads();
    if (jc == 3) {
        #pragma unroll
        for (int d = 0; d < 16; ++d)
            kqkv[e0 + d][lane] = (kqkv[e0 + d][lane] + po[d]) * inv;
    }
    __syncthreads();
    {
        int e = tid >> 4, part = tid & 15;
        float4 v = *(const float4*)&kqkv[e][part * 4];
        pool_s[e][part] = v.x + v.y + v.z + v.w;
    }
    __syncthreads();
    if (tid < 64) {
        float s = 0.f;
        #pragma unroll
        for (int p = 0; p < 16; ++p) s += pool_s[tid][p];
        mo[tid] = s * (1.f / 64.f);
    }
    __syncthreads();
    if (tid < 64) {
        float a = bout[tid];
        const float4* wr = (const float4*)(Wout + tid * 64);
        #pragma unroll
        for (int d4 = 0; d4 < 16; ++d4) {
            float4 w = wr[d4];
            a += mo[d4 * 4 + 0] * w.x + mo[d4 * 4 + 1] * w.y
               + mo[d4 * 4 + 2] * w.z + mo[d4 * 4 + 3] * w.w;
        }
        feat[b * NE + tid] = a;
    }
}

// ---------------------------------------------------------------------------
extern "C" void kernel_launch(void* const* d_in, const int* in_sizes, int n_in,
                              void* d_out, int out_size, void* d_ws, size_t ws_size,
                              hipStream_t stream) {
    const float* eeg      = (const float*)d_in[0];
    const float* gcn1_w   = (const float*)d_in[1];
    const float* gcn1_b   = (const float*)d_in[2];
    const float* gcn2_w   = (const float*)d_in[3];
    const float* gcn2_b   = (const float*)d_in[4];
    const float* bn1_g    = (const float*)d_in[5];
    const float* bn1_b    = (const float*)d_in[6];
    const float* bn2_g    = (const float*)d_in[7];
    const float* bn2_b    = (const float*)d_in[8];
    const float* attn_in_w  = (const float*)d_in[9];
    const float* attn_in_b  = (const float*)d_in[10];
    const float* attn_out_w = (const float*)d_in[11];
    const float* attn_out_b = (const float*)d_in[12];

    float* out  = (float*)d_out;
    float* feat = out;                          // [B, E]
    float* wpli = out + NB * NE;                // [B, C, C]

    float* ws = (float*)d_ws;
    float*  w_re   = ws;                        // [1M]
    float*  w_im   = ws + 1048576;              // [1M]
    float*  w_x1   = ws + 2097152;              // [1M]
    float*  w_x2   = ws + 3145728;              // [512K]
    float*  w_deg  = ws + 3670016;              // [8K]
    double* dpart1 = (double*)(ws + 3678208);   // [128*64*2]
    double* dpart2 = (double*)(ws + 3710976);   // [128*64*2]

    // 1. analytic signal
    analytic_kernel<<<NB * NC, NT, 0, stream>>>(eeg, w_re, w_im);
    // 2. PLI (+deg), writes wpli output
    pli_kernel<<<NB * NC / 4, 256, 0, stream>>>(w_re, w_im, wpli, w_deg);
    // 3. GCN1 fused, 2 blocks/batch (grid 256 = all CUs)
    gcn_fused<HIDN, false><<<NB * 2, 1024, 0, stream>>>(
        wpli, w_deg, eeg, nullptr, nullptr, nullptr,
        gcn1_w, gcn1_b, w_x1, dpart1);
    // 4. GCN2 fused, 2 blocks/batch
    gcn_fused<NE, true><<<NB * 2, 1024, 0, stream>>>(
        wpli, w_deg, w_x1, dpart1, bn1_g, bn1_b,
        gcn2_w, gcn2_b, w_x2, dpart2);
    // 5. attention fused
    attn_fused<<<NB, 1024, 0, stream>>>(w_x2, dpart2, bn2_g, bn2_b,
                                        attn_in_w, attn_in_b,
                                        attn_out_w, attn_out_b, feat);
}

// Round 10
// 98.581 us; speedup vs baseline: 2.7646x; 1.0473x over previous
//
#include <hip/hip_runtime.h>
#include <math.h>

#define NB 128     // batch
#define NC 64      // channels
#define NT 128     // segment length
#define HIDN 128   // hidden
#define NE 64      // attn embed
#define NHD 4      // heads
#define HD 16      // head dim

// ---------------------------------------------------------------------------
// 1. Analytic signal (unchanged; bit-identical math; [b][c][t] layout).
// ---------------------------------------------------------------------------
__global__ void analytic_kernel(const float* __restrict__ eeg,
                                float* __restrict__ re, float* __restrict__ im) {
    int row = blockIdx.x;            // b*NC + c
    int t = threadIdx.x;             // 0..127
    __shared__ float xs[NT];
    __shared__ double cotv[64];
    xs[t] = eeg[row * NT + t];
    if (t < 64) {
        double d = (double)(2 * t + 1);
        double a = 3.14159265358979323846 * d / 128.0;
        cotv[t] = cos(a) / sin(a);
    }
    __syncthreads();
    double ar = 0.0, ai = 0.0;
    #pragma unroll
    for (int m = 0; m < 64; ++m) {
        int d = 2 * m + 1;
        int s = (t - d) & 127;
        double xv = (double)xs[s];
        ar += xv;
        ai += cotv[m] * xv;
    }
    double rr = (double)xs[t] + ar * (1.0 / 64.0);
    double ii = ai * (1.0 / 64.0);
    re[row * NT + t] = (float)rr;
    im[row * NT + t] = (float)ii;
}

// ---------------------------------------------------------------------------
// 2. PLI v3 (unchanged). Bit-identical accumulation.
// ---------------------------------------------------------------------------
__global__ void pli_kernel(const float* __restrict__ re, const float* __restrict__ im,
                           float* __restrict__ wpli, float* __restrict__ deg) {
    int b = blockIdx.x >> 4;
    int i0 = (blockIdx.x & 15) << 2;
    int tid = threadIdx.x;           // 256
    int w = tid >> 6;
    int j = tid & 63;
    __shared__ float4 sre4[64 * 32];
    __shared__ float4 sim4[64 * 32];
    __shared__ int pacc[4][4][64];
    const float* reb = re + b * (NC * NT);
    const float* imb = im + b * (NC * NT);
    for (int idx4 = tid; idx4 < 2048; idx4 += 256) {
        int c = idx4 >> 5, t4 = idx4 & 31;
        int slot = c * 32 + (t4 ^ (c & 31));
        sre4[slot] = ((const float4*)reb)[idx4];
        sim4[slot] = ((const float4*)imb)[idx4];
    }
    __syncthreads();
    int acc0 = 0, acc1 = 0, acc2 = 0, acc3 = 0;
    #pragma unroll
    for (int tt = 0; tt < 8; ++tt) {
        int t4 = w * 8 + tt;
        float4 rj = sre4[j * 32 + (t4 ^ (j & 31))];
        float4 ij = sim4[j * 32 + (t4 ^ (j & 31))];
        #pragma unroll
        for (int di = 0; di < 4; ++di) {
            int i = i0 + di;
            float4 ri = sre4[i * 32 + (t4 ^ (i & 31))];
            float4 ii = sim4[i * 32 + (t4 ^ (i & 31))];
            float c0 = ii.x * rj.x - ri.x * ij.x;
            float c1 = ii.y * rj.y - ri.y * ij.y;
            float c2 = ii.z * rj.z - ri.z * ij.z;
            float c3 = ii.w * rj.w - ri.w * ij.w;
            int d = ((c0 > 0.f) ? 1 : ((c0 < 0.f) ? -1 : 0))
                  + ((c1 > 0.f) ? 1 : ((c1 < 0.f) ? -1 : 0))
                  + ((c2 > 0.f) ? 1 : ((c2 < 0.f) ? -1 : 0))
                  + ((c3 > 0.f) ? 1 : ((c3 < 0.f) ? -1 : 0));
            if (di == 0) acc0 += d;
            else if (di == 1) acc1 += d;
            else if (di == 2) acc2 += d;
            else acc3 += d;
        }
    }
    pacc[w][0][j] = acc0; pacc[w][1][j] = acc1;
    pacc[w][2][j] = acc2; pacc[w][3][j] = acc3;
    __syncthreads();
    int di2 = tid >> 6, j2 = tid & 63;
    int a = pacc[0][di2][j2] + pacc[1][di2][j2] + pacc[2][di2][j2] + pacc[3][di2][j2];
    float p = fabsf((float)a * (1.f / (float)NT));
    int i = i0 + di2;
    if (j2 == i) p = 0.f;
    wpli[b * (NC * NC) + i * NC + j2] = p;
    float s = p;
    #pragma unroll
    for (int off = 32; off > 0; off >>= 1) s += __shfl_down(s, off);
    if (j2 == 0) deg[b * NC + i] = s;
}

// ---------------------------------------------------------------------------
// 3. Fused GCN layer, 2 blocks per batch (unchanged from R9).
// ---------------------------------------------------------------------------
template <int OUT, bool BN_IN>
__global__ __launch_bounds__(1024, 1) void gcn_fused(
        const float* __restrict__ adj, const float* __restrict__ deg,
        const float* __restrict__ x, const double* __restrict__ dpart_in,
        const float* __restrict__ g, const float* __restrict__ bb,
        const float* __restrict__ W, const float* __restrict__ bias,
        float* __restrict__ xout, double* __restrict__ dpart_out) {
    int b = blockIdx.x >> 1;
    int half = blockIdx.x & 1;
    int tid = threadIdx.x;           // 1024
    __shared__ float dn_s[64];
    __shared__ float stat_s[64][2];
    __shared__ float arow[32][68];
    __shared__ float xs[64][128];
    __shared__ float sup[32][132];
    __shared__ float WsT[128][(OUT == 128) ? 132 : 68];  // [k][o]
    __shared__ double dred[16][64][2];

    if (BN_IN) {
        int c = tid & 63, chunk = tid >> 6;
        double s = 0.0, s2 = 0.0;
        for (int bi = chunk * 8; bi < chunk * 8 + 8; ++bi) {
            s  += dpart_in[(bi * 64 + c) * 2];
            s2 += dpart_in[(bi * 64 + c) * 2 + 1];
        }
        dred[chunk][c][0] = s;
        dred[chunk][c][1] = s2;
    }
    if (tid < 64)
        dn_s[tid] = (float)(1.0 / sqrt((double)deg[b * 64 + tid] + 1e-8));
    __syncthreads();
    if (BN_IN && tid < 64) {
        double s = 0.0, s2 = 0.0;
        for (int ch = 0; ch < 16; ++ch) {
            s  += dred[ch][tid][0];
            s2 += dred[ch][tid][1];
        }
        double N = (double)(NB * HIDN);
        double m = s / N;
        double var = s2 / N - m * m;
        stat_s[tid][0] = (float)m;
        stat_s[tid][1] = (float)(1.0 / sqrt(var + 1e-5));
    }
    __syncthreads();
    if (tid < 512) {
        int il = tid >> 4, j4 = tid & 15;
        int i = half * 32 + il;
        float4 v = *(const float4*)&adj[b * 4096 + i * 64 + j4 * 4];
        float di = dn_s[i];
        v.x *= di * dn_s[j4 * 4 + 0];
        v.y *= di * dn_s[j4 * 4 + 1];
        v.z *= di * dn_s[j4 * 4 + 2];
        v.w *= di * dn_s[j4 * 4 + 3];
        *(float4*)&arow[il][j4 * 4] = v;
    }
    #pragma unroll
    for (int p = 0; p < 2; ++p) {
        int idx4 = tid + p * 1024;
        int r = idx4 >> 5, c4 = idx4 & 31;
        float4 v = ((const float4*)(x + b * 8192))[idx4];
        if (BN_IN) {
            float m = stat_s[r][0], rs = stat_s[r][1], gg = g[r], bv = bb[r];
            v.x = (v.x - m) * rs * gg + bv; v.x = v.x > 0.f ? v.x : 0.f;
            v.y = (v.y - m) * rs * gg + bv; v.y = v.y > 0.f ? v.y : 0.f;
            v.z = (v.z - m) * rs * gg + bv; v.z = v.z > 0.f ? v.z : 0.f;
            v.w = (v.w - m) * rs * gg + bv; v.w = v.w > 0.f ? v.w : 0.f;
        }
        *(float4*)&xs[r][c4 * 4] = v;
    }
    #pragma unroll
    for (int p = 0; p < OUT / 32; ++p) {
        int idx4 = tid + p * 1024;
        int o = idx4 & (OUT - 1);
        int k4 = idx4 / OUT;
        float4 w = *(const float4*)&W[o * 128 + k4 * 4];
        WsT[k4 * 4 + 0][o] = w.x;
        WsT[k4 * 4 + 1][o] = w.y;
        WsT[k4 * 4 + 2][o] = w.z;
        WsT[k4 * 4 + 3][o] = w.w;
    }
    __syncthreads();

    int il = tid >> 5;
    int i = half * 32 + il;
    {
        int f0 = (tid & 31) * 4;
        float a0 = 0.f, a1 = 0.f, a2 = 0.f, a3 = 0.f;
        #pragma unroll 8
        for (int j = 0; j < 64; ++j) {
            float a = arow[il][j];
            float4 xv = *(const float4*)&xs[j][f0];
            a0 += a * xv.x; a1 += a * xv.y; a2 += a * xv.z; a3 += a * xv.w;
        }
        *(float4*)&sup[il][f0] = make_float4(a0, a1, a2, a3);
    }
    __syncthreads();

    double ds = 0.0, ds2 = 0.0;
    if (OUT == 128) {
        int o0 = (tid & 31) * 4;
        float c[4] = {};
        #pragma unroll 8
        for (int k = 0; k < 128; ++k) {
            float s = sup[il][k];
            float4 w0 = *(const float4*)&WsT[k][o0];
            c[0] += s * w0.x; c[1] += s * w0.y; c[2] += s * w0.z; c[3] += s * w0.w;
        }
        float4 r0 = make_float4(c[0] + bias[o0], c[1] + bias[o0 + 1],
                                c[2] + bias[o0 + 2], c[3] + bias[o0 + 3]);
        *(float4*)&xout[b * 64 * 128 + i * 128 + o0] = r0;
        ds  = (double)r0.x + (double)r0.y + (double)r0.z + (double)r0.w;
        ds2 = (double)r0.x * r0.x + (double)r0.y * r0.y
            + (double)r0.z * r0.z + (double)r0.w * r0.w;
    } else {
        int o0 = (tid & 31) * 2;
        float c0 = 0.f, c1 = 0.f;
        #pragma unroll 8
        for (int k = 0; k < 128; ++k) {
            float s = sup[il][k];
            c0 += s * WsT[k][o0];
            c1 += s * WsT[k][o0 + 1];
        }
        c0 += bias[o0];
        c1 += bias[o0 + 1];
        *(float2*)&xout[b * 64 * 64 + i * 64 + o0] = make_float2(c0, c1);
        ds  = (double)c0 + (double)c1;
        ds2 = (double)c0 * c0 + (double)c1 * c1;
    }
    #pragma unroll
    for (int off = 16; off > 0; off >>= 1) {
        ds  += __shfl_down(ds, off, 32);
        ds2 += __shfl_down(ds2, off, 32);
    }
    if ((tid & 31) == 0) {
        dpart_out[(b * 64 + i) * 2]     = ds;
        dpart_out[(b * 64 + i) * 2 + 1] = ds2;
    }
}

// ---------------------------------------------------------------------------
// 4. Attention v6: one block per (b, head), 256 threads (wave = j-chunk).
//    Redundant per-block BN2 stat reduce (4-way parallel, fixed order),
//    stage x (BN2+ReLU) + head's 48 W rows, QKV reg-tile, R7 softmax/PV
//    structure, pooled means -> w_mo[b][h*16+d].  ~49 KB LDS -> 2+ blk/CU.
// ---------------------------------------------------------------------------
__global__ __launch_bounds__(256) void attn_head(
        const float* __restrict__ x2, const double* __restrict__ dpart2,
        const float* __restrict__ g, const float* __restrict__ bb,
        const float* __restrict__ Win, const float* __restrict__ bin,
        float* __restrict__ w_mo) {
    int b = blockIdx.x >> 2, h = blockIdx.x & 3;
    int tid = threadIdx.x;
    int lane = tid & 63, wv = tid >> 6;   // wv = j-chunk (wave-uniform)
    __shared__ double dred[4][64][2];     // 4 KB
    __shared__ float stat_s[64][2];
    __shared__ float xs[64][68];          // 17.4 KB
    __shared__ float ws[48][64];          // 12 KB (q 0..15, k 16..31, v 32..47)
    __shared__ float kqkv[48][64];        // 12 KB ([dim][n]; q rows become ao)
    __shared__ float pm_s[4][64], ps_s[4][64];
    __shared__ float pool_s[16][17];

    {   // BN2 stats: 4-way chunked partial reduce (fixed order)
        double s = 0.0, s2 = 0.0;
        for (int bi = wv * 32; bi < wv * 32 + 32; ++bi) {
            s  += dpart2[(bi * 64 + lane) * 2];
            s2 += dpart2[(bi * 64 + lane) * 2 + 1];
        }
        dred[wv][lane][0] = s;
        dred[wv][lane][1] = s2;
    }
    __syncthreads();
    if (tid < 64) {
        double s  = dred[0][tid][0] + dred[1][tid][0] + dred[2][tid][0] + dred[3][tid][0];
        double s2 = dred[0][tid][1] + dred[1][tid][1] + dred[2][tid][1] + dred[3][tid][1];
        double N = (double)(NB * NE);
        double m = s / N;
        double var = s2 / N - m * m;
        stat_s[tid][0] = (float)m;
        stat_s[tid][1] = (float)(1.0 / sqrt(var + 1e-5));
    }
    __syncthreads();
    // stage x (BN2+ReLU)
    for (int idx4 = tid; idx4 < 1024; idx4 += 256) {
        int r = idx4 >> 4, c4 = idx4 & 15;
        float4 v = ((const float4*)(x2 + b * 4096))[idx4];
        float m = stat_s[r][0], rs = stat_s[r][1], gg = g[r], bv = bb[r];
        v.x = (v.x - m) * rs * gg + bv; v.x = v.x > 0.f ? v.x : 0.f;
        v.y = (v.y - m) * rs * gg + bv; v.y = v.y > 0.f ? v.y : 0.f;
        v.z = (v.z - m) * rs * gg + bv; v.z = v.z > 0.f ? v.z : 0.f;
        v.w = (v.w - m) * rs * gg + bv; v.w = v.w > 0.f ? v.w : 0.f;
        *(float4*)&xs[r][c4 * 4] = v;
    }
    // stage this head's 48 W rows
    for (int idx4 = tid; idx4 < 768; idx4 += 256) {
        int rl = idx4 >> 4, c4 = idx4 & 15;
        int rg = ((rl >> 4) << 6) + (h << 4) + (rl & 15);
        *(float4*)&ws[rl][c4 * 4] = ((const float4*)(Win + rg * 64))[c4];
    }
    __syncthreads();

    // --- QKV: thread (lane=n, wv); 12 outputs ol = wv + 4u ---
    float acc[12];
    #pragma unroll
    for (int u = 0; u < 12; ++u) {
        int ol = wv + 4 * u;
        acc[u] = bin[((ol >> 4) << 6) + (h << 4) + (ol & 15)];
    }
    #pragma unroll
    for (int d4 = 0; d4 < 16; ++d4) {
        float4 xv = *(const float4*)&xs[lane][d4 * 4];
        #pragma unroll
        for (int u = 0; u < 12; ++u) {
            float4 w = *(const float4*)&ws[wv + 4 * u][d4 * 4];   // broadcast
            acc[u] += xv.x * w.x + xv.y * w.y + xv.z * w.z + xv.w * w.w;
        }
    }
    #pragma unroll
    for (int u = 0; u < 12; ++u) kqkv[wv + 4 * u][lane] = acc[u];
    __syncthreads();

    // --- scores: thread (jc=wv, n=lane), 16 keys ---
    int j0 = wv * 16;
    float q[16];
    #pragma unroll
    for (int d = 0; d < 16; ++d) q[d] = kqkv[d][lane];
    float sc[16];
    #pragma unroll
    for (int jj = 0; jj < 16; ++jj) sc[jj] = 0.f;
    #pragma unroll
    for (int d = 0; d < 16; ++d) {
        float qd = q[d];
        #pragma unroll
        for (int j4 = 0; j4 < 4; ++j4) {
            float4 kv = *(const float4*)&kqkv[16 + d][j0 + j4 * 4]; // uniform
            sc[j4 * 4 + 0] += qd * kv.x;
            sc[j4 * 4 + 1] += qd * kv.y;
            sc[j4 * 4 + 2] += qd * kv.z;
            sc[j4 * 4 + 3] += qd * kv.w;
        }
    }
    float pmax = -1e30f;
    #pragma unroll
    for (int jj = 0; jj < 16; ++jj) { sc[jj] *= 0.25f; pmax = fmaxf(pmax, sc[jj]); }
    pm_s[wv][lane] = pmax;
    __syncthreads();
    float mx = fmaxf(fmaxf(pm_s[0][lane], pm_s[1][lane]),
                     fmaxf(pm_s[2][lane], pm_s[3][lane]));
    float psum = 0.f;
    #pragma unroll
    for (int jj = 0; jj < 16; ++jj) { sc[jj] = expf(sc[jj] - mx); psum += sc[jj]; }
    ps_s[wv][lane] = psum;
    float po[16];
    #pragma unroll
    for (int d = 0; d < 16; ++d) {
        float4 v0 = *(const float4*)&kqkv[32 + d][j0 + 0];          // uniform
        float4 v1 = *(const float4*)&kqkv[32 + d][j0 + 4];
        float4 v2 = *(const float4*)&kqkv[32 + d][j0 + 8];
        float4 v3 = *(const float4*)&kqkv[32 + d][j0 + 12];
        po[d] = sc[0] * v0.x + sc[1] * v0.y + sc[2] * v0.z + sc[3] * v0.w
              + sc[4] * v1.x + sc[5] * v1.y + sc[6] * v1.z + sc[7] * v1.w
              + sc[8] * v2.x + sc[9] * v2.y + sc[10] * v2.z + sc[11] * v2.w
              + sc[12] * v3.x + sc[13] * v3.y + sc[14] * v3.z + sc[15] * v3.w;
    }
    __syncthreads();
    float inv = 1.f / (ps_s[0][lane] + ps_s[1][lane] + ps_s[2][lane] + ps_s[3][lane]);
    // combine PV partials into dead q rows, deterministic jc order
    if (wv == 0) {
        #pragma unroll
        for (int d = 0; d < 16; ++d) kqkv[d][lane] = po[d];
    }
    __syncthreads();
    if (wv == 1) {
        #pragma unroll
        for (int d = 0; d < 16; ++d) kqkv[d][lane] += po[d];
    }
    __syncthreads();
    if (wv == 2) {
        #pragma unroll
        for (int d = 0; d < 16; ++d) kqkv[d][lane] += po[d];
    }
    __syncthreads();
    if (wv == 3) {
        #pragma unroll
        for (int d = 0; d < 16; ++d)
            kqkv[d][lane] = (kqkv[d][lane] + po[d]) * inv;
    }
    __syncthreads();
    // --- pool over n: 16 partials per d ---
    {
        int d = tid & 15, part = tid >> 4;
        float4 v = *(const float4*)&kqkv[d][part * 4];
        pool_s[d][part] = v.x + v.y + v.z + v.w;
    }
    __syncthreads();
    if (tid < 16) {
        float s = 0.f;
        #pragma unroll
        for (int p = 0; p < 16; ++p) s += pool_s[tid][p];
        w_mo[b * 64 + h * 16 + tid] = s * (1.f / 64.f);
    }
}

// ---------------------------------------------------------------------------
// 5. Output projection: feat[b][e] = bout[e] + sum_d Wout[e][d] * mo[b][d]
// ---------------------------------------------------------------------------
__global__ void proj_kernel(const float* __restrict__ w_mo,
                            const float* __restrict__ Wout,
                            const float* __restrict__ bout,
                            float* __restrict__ feat) {
    int b = blockIdx.x;
    int tid = threadIdx.x;           // 0..63
    __shared__ float mos[64];
    mos[tid] = w_mo[b * 64 + tid];
    __syncthreads();
    float acc = bout[tid];
    const float4* wr = (const float4*)(Wout + tid * 64);
    #pragma unroll
    for (int d4 = 0; d4 < 16; ++d4) {
        float4 w = wr[d4];
        acc += mos[d4 * 4 + 0] * w.x + mos[d4 * 4 + 1] * w.y
             + mos[d4 * 4 + 2] * w.z + mos[d4 * 4 + 3] * w.w;
    }
    feat[b * NE + tid] = acc;
}

// ---------------------------------------------------------------------------
extern "C" void kernel_launch(void* const* d_in, const int* in_sizes, int n_in,
                              void* d_out, int out_size, void* d_ws, size_t ws_size,
                              hipStream_t stream) {
    const float* eeg      = (const float*)d_in[0];
    const float* gcn1_w   = (const float*)d_in[1];
    const float* gcn1_b   = (const float*)d_in[2];
    const float* gcn2_w   = (const float*)d_in[3];
    const float* gcn2_b   = (const float*)d_in[4];
    const float* bn1_g    = (const float*)d_in[5];
    const float* bn1_b    = (const float*)d_in[6];
    const float* bn2_g    = (const float*)d_in[7];
    const float* bn2_b    = (const float*)d_in[8];
    const float* attn_in_w  = (const float*)d_in[9];
    const float* attn_in_b  = (const float*)d_in[10];
    const float* attn_out_w = (const float*)d_in[11];
    const float* attn_out_b = (const float*)d_in[12];

    float* out  = (float*)d_out;
    float* feat = out;                          // [B, E]
    float* wpli = out + NB * NE;                // [B, C, C]

    float* ws = (float*)d_ws;
    float*  w_re   = ws;                        // [1M]
    float*  w_im   = ws + 1048576;              // [1M]
    float*  w_x1   = ws + 2097152;              // [1M]
    float*  w_x2   = ws + 3145728;              // [512K]
    float*  w_deg  = ws + 3670016;              // [8K]
    float*  w_mo   = ws + 3678208;              // [8K]
    double* dpart1 = (double*)(ws + 3686400);   // [128*64*2]
    double* dpart2 = (double*)(ws + 3719168);   // [128*64*2]

    // 1. analytic signal
    analytic_kernel<<<NB * NC, NT, 0, stream>>>(eeg, w_re, w_im);
    // 2. PLI (+deg), writes wpli output
    pli_kernel<<<NB * NC / 4, 256, 0, stream>>>(w_re, w_im, wpli, w_deg);
    // 3. GCN1 fused, 2 blocks/batch
    gcn_fused<HIDN, false><<<NB * 2, 1024, 0, stream>>>(
        wpli, w_deg, eeg, nullptr, nullptr, nullptr,
        gcn1_w, gcn1_b, w_x1, dpart1);
    // 4. GCN2 fused, 2 blocks/batch
    gcn_fused<NE, true><<<NB * 2, 1024, 0, stream>>>(
        wpli, w_deg, w_x1, dpart1, bn1_g, bn1_b,
        gcn2_w, gcn2_b, w_x2, dpart2);
    // 5. attention per (b, head): 512 blocks
    attn_head<<<NB * NHD, 256, 0, stream>>>(w_x2, dpart2, bn2_g, bn2_b,
                                            attn_in_w, attn_in_b, w_mo);
    // 6. output projection
    proj_kernel<<<NB, NE, 0, stream>>>(w_mo, attn_out_w, attn_out_b, feat);
}